// Round 10
// baseline (118.436 us; speedup 1.0000x reference)
//
#include <hip/hip_runtime.h>
#include <hip/hip_cooperative_groups.h>
#include <math.h>

namespace cg = cooperative_groups;

#define BS 16
#define NGT 64
#define NA 8400
#define NCLS 80
#define NCAND 27
#define WND 84           // anchors per phase-2 block; 100 windows * 84 = 8400 exact
#define NWIN 100
#define FINF 3.4e38f

typedef float floatx4 __attribute__((ext_vector_type(4)));

__device__ __forceinline__ float pair_iou(float gx1, float gy1, float gx2, float gy2,
                                          float ax1, float ay1, float ax2, float ay2) {
    // _pairwise_iou semantics: unclamped areas, union = max(a1+a2-ov, 1e-6)
    float ltx = fmaxf(gx1, ax1), lty = fmaxf(gy1, ay1);
    float rbx = fminf(gx2, ax2), rby = fminf(gy2, ay2);
    float w = fmaxf(rbx - ltx, 0.0f), h = fmaxf(rby - lty, 0.0f);
    float ov = w * h;
    float a1 = (gx2 - gx1) * (gy2 - gy1);
    float a2 = (ax2 - ax1) * (ay2 - ay1);
    float uni = fmaxf(a1 + a2 - ov, 1e-6f);
    return ov / uni;
}

// Phase 1 (== R8 k1 body, absmax-0 since R5): one wave per (b,g) row.
// Geometric exact top-9 (uniform-grid anchors => per-level top-9 lies in the
// 4x4 window around the gt center cell; rank-by-comparison == lax.top_k
// order). Emits the compact 27-slot list, every slot written unconditionally.
// Barrier-free: siou_row is wave-private LDS (within-wave ds ordering, proven
// in the R7 fused kernel).
__device__ __forceinline__ void phase1_row(
        const int row, const int lane, float* siou_row,
        const float* __restrict__ anc, const float* __restrict__ gtb,
        const float* __restrict__ mgt, unsigned int* __restrict__ clist) {
    const int g = row & 63;
    const bool vrow = mgt[row] > 0.0f;

    const float4 gb = ((const float4*)gtb)[row];
    const float gcx = (gb.x + gb.z) * 0.5f, gcy = (gb.y + gb.w) * 0.5f;

    const int lev = lane >> 4, jj = lane & 15;
    float d = FINF; int aidx = 0x7fffffff;
    float iou = 0.0f, mn = -1.0f;
    if (lev < 3) {
        const int n    = (lev == 0) ? 80 : (lev == 1) ? 40 : 20;
        const int base = (lev == 0) ? 0 : (lev == 1) ? 6400 : 8000;
        const float s  = (float)(8 << lev);
        int ix0 = (int)floorf(gcx / s - 0.5f) - 1;
        int iy0 = (int)floorf(gcy / s - 0.5f) - 1;
        ix0 = min(max(ix0, 0), n - 4);
        iy0 = min(max(iy0, 0), n - 4);
        const int ix = ix0 + (jj & 3), iy = iy0 + (jj >> 2);
        aidx = base + iy * n + ix;
        // distance/IoU/margin: textually identical to the absmax-0 kernels
        const float4 ab = ((const float4*)anc)[aidx];
        const float acx = (ab.x + ab.z) * 0.5f, acy = (ab.y + ab.w) * 0.5f;
        const float dx = gcx - acx, dy = gcy - acy;
        d = sqrtf(dx * dx + dy * dy);
        iou = pair_iou(gb.x, gb.y, gb.z, gb.w, ab.x, ab.y, ab.z, ab.w);
        mn = fminf(fminf(acx - gb.x, acy - gb.y), fminf(gb.z - acx, gb.w - acy));
    }

    // rank within the 16-lane group by lexicographic (d, idx) ascending
    const int grpbase = lane & 48;
    int rank = 0;
#pragma unroll
    for (int t = 0; t < 16; ++t) {
        const float od = __shfl(d, grpbase + t);
        const int   oi = __shfl(aidx, grpbase + t);
        rank += (od < d || (od == d && oi < aidx)) ? 1 : 0;
    }
    const bool cand = (lev < 3) && (rank < 9);

    if (cand && vrow) siou_row[lev * 9 + rank] = iou;    // candidate order == top_k;
                                                         // within-wave LDS ordering
    // mean + std(ddof=1) in the SAME k=0..26 sequence as the passing kernels
    float sum = 0.0f;
#pragma unroll
    for (int k = 0; k < NCAND; ++k) sum += siou_row[k];
    const float mean = sum / (float)NCAND;
    float vs = 0.0f;
#pragma unroll
    for (int k = 0; k < NCAND; ++k) { float dd = siou_row[k] - mean; vs += dd * dd; }
    const float thr = mean + sqrtf(vs / (float)(NCAND - 1));

    if (cand) {   // every (lev,rank<9) slot has exactly one owner -> full coverage
        unsigned int v = 0xFFFFFFFFu;
        if (vrow && iou > thr && mn > 1e-9f)             // strict >, EPS=1e-9
            v = (unsigned int)aidx | ((unsigned int)g << 14);   // aidx<2^14, g<2^6
        clist[row * NCAND + lev * 9 + rank] = v;
    }
}

// Phase 2 (== R8 k23 body): one block per (b, 84-anchor window). Scan the
// batch's 1728-entry list into LDS, resolve, stream outputs (scores NT).
__device__ __forceinline__ void phase2_win(
        const int bidx, const int tid,
        unsigned int* lacc, int* slbl, float* sv,
        const float* __restrict__ anc, const int* __restrict__ glab,
        const float* __restrict__ gtb, const float* __restrict__ pdb,
        const unsigned int* __restrict__ clist, float* __restrict__ out) {
    const int b = bidx / NWIN, win = bidx - b * NWIN;
    const int a0 = win * WND;

    if (tid < WND) lacc[tid] = 0u;
    __syncthreads();

    const unsigned int* lst = clist + b * (NGT * NCAND);
    for (int e = tid; e < NGT * NCAND; e += 256) {
        const unsigned int u = lst[e];
        if (u != 0xFFFFFFFFu) {
            const int rel = (int)(u & 0x3FFFu) - a0;
            if (rel >= 0 && rel < WND)
                atomicAdd(&lacc[rel], (1u << 20) | (u >> 14));
        }
    }
    __syncthreads();

    if (tid < WND) {
        const int a = a0 + tid;
        const int idx = b * NA + a;
        const unsigned int acc = lacc[tid];
        const unsigned int fg = acc >> 20;
        int tgi = 0;
        if (fg == 1) {
            tgi = (int)(acc & 0xFFFFFu);             // sum of one g == that g
        } else if (fg > 1) {                         // argmax over ALL 64 gts
            const float4 ab = ((const float4*)anc)[a];
            float best = -1.0f; int gi = 0;
            for (int g = 0; g < NGT; ++g) {
                const float* gp = gtb + (b * NGT + g) * 4;
                float v = pair_iou(gp[0], gp[1], gp[2], gp[3], ab.x, ab.y, ab.z, ab.w);
                if (v > best) { best = v; gi = g; }
            }
            tgi = gi;
        }
        const bool pos = fg > 0;
        const int lbl = pos ? glab[b * NGT + tgi] : NCLS;
        const float4 gbox = ((const float4*)gtb)[b * NGT + tgi];

        float sval = 0.0f;
        if (pos) {
            // _batch_iou: clamped areas, union = a1+a2-ov+1e-9 (no max)
            const float4 pp = ((const float4*)pdb)[idx];
            float ltx = fmaxf(gbox.x, pp.x), lty = fmaxf(gbox.y, pp.y);
            float rbx = fminf(gbox.z, pp.z), rby = fminf(gbox.w, pp.w);
            float ov = fmaxf(rbx - ltx, 0.0f) * fmaxf(rby - lty, 0.0f);
            float a1 = fmaxf(gbox.z - gbox.x, 0.0f) * fmaxf(gbox.w - gbox.y, 0.0f);
            float a2 = fmaxf(pp.z - pp.x, 0.0f) * fmaxf(pp.w - pp.y, 0.0f);
            sval = ov / (a1 + a2 - ov + 1e-9f);
        }

        out[idx] = (float)lbl;                                 // target_labels
        ((float4*)(out + (size_t)BS * NA))[idx] = gbox;        // target_bboxes
        out[(size_t)BS * NA * 85 + idx] = pos ? 1.0f : 0.0f;   // fg_mask
        slbl[tid] = lbl; sv[tid] = sval;
    }
    __syncthreads();

    // stream scores NT: contiguous [ (b*NA+a0)*80, +WND*80 ) floats = 26.9 KB
    floatx4* ob = (floatx4*)(out + (size_t)BS * NA * 5 + ((size_t)b * NA + a0) * NCLS);
    for (int s = tid; s < WND * (NCLS / 4); s += 256) {
        const int lba = s / (NCLS / 4);
        const int q = s - lba * (NCLS / 4);
        const int lbl = slbl[lba];
        const float v = sv[lba];
        const int c0 = q * 4;
        floatx4 r;
        r.x = (c0     == lbl) ? v : 0.0f;
        r.y = (c0 + 1 == lbl) ? v : 0.0f;
        r.z = (c0 + 2 == lbl) ? v : 0.0f;
        r.w = (c0 + 3 == lbl) ? v : 0.0f;
        __builtin_nontemporal_store(r, &ob[s]);
    }
}

// Cooperative fused kernel: blocks 0..255 run phase 1 (one wave per gt row),
// grid-wide sync, then all 1600 blocks run phase 2. __launch_bounds__(256,7)
// caps VGPR so >=7 blocks/CU co-reside (1600 <= 7*256), satisfying the
// cooperative-launch check.
__global__ __launch_bounds__(256, 7) void atss_coop(
        const float* __restrict__ anc, const int* __restrict__ glab,
        const float* __restrict__ gtb, const float* __restrict__ mgt,
        const float* __restrict__ pdb, unsigned int* __restrict__ clist,
        float* __restrict__ out) {
    __shared__ float siou[4][28];
    __shared__ unsigned int lacc[WND];
    __shared__ int   slbl[WND];
    __shared__ float sv[WND];

    const int tid = threadIdx.x, wv = tid >> 6, lane = tid & 63;
    if (blockIdx.x < (BS * NGT) / 4)
        phase1_row(blockIdx.x * 4 + wv, lane, siou[wv], anc, gtb, mgt, clist);

    cg::this_grid().sync();

    phase2_win(blockIdx.x, tid, lacc, slbl, sv, anc, glab, gtb, pdb, clist, out);
}

// Fallback path (proven 27.1 µs R8 structure) if cooperative launch is rejected.
__global__ __launch_bounds__(256) void k1_fb(
        const float* __restrict__ anc, const float* __restrict__ gtb,
        const float* __restrict__ mgt, unsigned int* __restrict__ clist) {
    __shared__ float siou[4][28];
    const int wv = threadIdx.x >> 6;
    phase1_row(blockIdx.x * 4 + wv, threadIdx.x & 63, siou[wv], anc, gtb, mgt, clist);
}

__global__ __launch_bounds__(256) void k23_fb(
        const float* __restrict__ anc, const int* __restrict__ glab,
        const float* __restrict__ gtb, const float* __restrict__ pdb,
        const unsigned int* __restrict__ clist, float* __restrict__ out) {
    __shared__ unsigned int lacc[WND];
    __shared__ int   slbl[WND];
    __shared__ float sv[WND];
    phase2_win(blockIdx.x, threadIdx.x, lacc, slbl, sv, anc, glab, gtb, pdb, clist, out);
}

extern "C" void kernel_launch(void* const* d_in, const int* in_sizes, int n_in,
                              void* d_out, int out_size, void* d_ws, size_t ws_size,
                              hipStream_t stream) {
    const float* anc  = (const float*)d_in[0];
    const int*   glab = (const int*)d_in[1];
    const float* gtb  = (const float*)d_in[2];
    const float* mgt  = (const float*)d_in[3];
    const float* pdb  = (const float*)d_in[4];
    float* out = (float*)d_out;

    // ws: clist u32[BS*NGT*27] (~110 KB), fully rewritten every call
    unsigned int* clist = (unsigned int*)d_ws;

    void* args[] = {(void*)&anc, (void*)&glab, (void*)&gtb, (void*)&mgt,
                    (void*)&pdb, (void*)&clist, (void*)&out};
    hipError_t e = hipLaunchCooperativeKernel(
        reinterpret_cast<const void*>(&atss_coop),
        dim3(BS * NWIN), dim3(256), args, 0, stream);
    if (e != hipSuccess) {   // deterministic fallback: proven 2-kernel path
        k1_fb<<<BS * NGT / 4, 256, 0, stream>>>(anc, gtb, mgt, clist);
        k23_fb<<<BS * NWIN, 256, 0, stream>>>(anc, glab, gtb, pdb, clist, out);
    }
}

// Round 11
// 25.883 us; speedup vs baseline: 4.5757x; 4.5757x over previous
//
#include <hip/hip_runtime.h>
#include <math.h>

#define BS 16
#define NGT 64
#define NA 8400
#define NCLS 80
#define NCAND 27
#define WND 84           // anchors per k23 block; 100 windows * 84 = 8400 exact
#define NWIN 100
#define FINF 3.4e38f

typedef float floatx4 __attribute__((ext_vector_type(4)));

__device__ __forceinline__ float pair_iou(float gx1, float gy1, float gx2, float gy2,
                                          float ax1, float ay1, float ax2, float ay2) {
    // _pairwise_iou semantics: unclamped areas, union = max(a1+a2-ov, 1e-6)
    float ltx = fmaxf(gx1, ax1), lty = fmaxf(gy1, ay1);
    float rbx = fminf(gx2, ax2), rby = fminf(gy2, ay2);
    float w = fmaxf(rbx - ltx, 0.0f), h = fmaxf(rby - lty, 0.0f);
    float ov = w * h;
    float a1 = (gx2 - gx1) * (gy2 - gy1);
    float a2 = (ax2 - ax1) * (ay2 - ay1);
    float uni = fmaxf(a1 + a2 - ov, 1e-6f);
    return ov / uni;
}

// K1 (unchanged, absmax-0 since R5): one wave per (b,g) row, 4 rows/block.
// Geometric exact top-9 (uniform-grid anchors => per-level top-9 lies in the
// 4x4 window around the gt center cell; rank-by-comparison == lax.top_k
// order). Emits a compact 27-slot list per row, every slot written
// unconditionally (positive or sentinel) -> no init pass, no atomics.
__global__ __launch_bounds__(256) void k1_candidates(
        const float* __restrict__ anc, const float* __restrict__ gtb,
        const float* __restrict__ mgt, unsigned int* __restrict__ clist) {
    const int tid = threadIdx.x, wid = tid >> 6, lane = tid & 63;
    const int row = blockIdx.x * 4 + wid;          // b*NGT + g
    const int g = row & 63;
    const bool vrow = mgt[row] > 0.0f;

    const float4 gb = ((const float4*)gtb)[row];
    const float gcx = (gb.x + gb.z) * 0.5f, gcy = (gb.y + gb.w) * 0.5f;

    const int lev = lane >> 4, jj = lane & 15;
    float d = FINF; int aidx = 0x7fffffff;
    float iou = 0.0f, mn = -1.0f;
    if (lev < 3) {
        const int n    = (lev == 0) ? 80 : (lev == 1) ? 40 : 20;
        const int base = (lev == 0) ? 0 : (lev == 1) ? 6400 : 8000;
        const float s  = (float)(8 << lev);
        int ix0 = (int)floorf(gcx / s - 0.5f) - 1;
        int iy0 = (int)floorf(gcy / s - 0.5f) - 1;
        ix0 = min(max(ix0, 0), n - 4);
        iy0 = min(max(iy0, 0), n - 4);
        const int ix = ix0 + (jj & 3), iy = iy0 + (jj >> 2);
        aidx = base + iy * n + ix;
        // distance/IoU/margin: textually identical to the absmax-0 kernels
        const float4 ab = ((const float4*)anc)[aidx];
        const float acx = (ab.x + ab.z) * 0.5f, acy = (ab.y + ab.w) * 0.5f;
        const float dx = gcx - acx, dy = gcy - acy;
        d = sqrtf(dx * dx + dy * dy);
        iou = pair_iou(gb.x, gb.y, gb.z, gb.w, ab.x, ab.y, ab.z, ab.w);
        mn = fminf(fminf(acx - gb.x, acy - gb.y), fminf(gb.z - acx, gb.w - acy));
    }

    // rank within the 16-lane group by lexicographic (d, idx) ascending
    const int grpbase = lane & 48;
    int rank = 0;
#pragma unroll
    for (int t = 0; t < 16; ++t) {
        const float od = __shfl(d, grpbase + t);
        const int   oi = __shfl(aidx, grpbase + t);
        rank += (od < d || (od == d && oi < aidx)) ? 1 : 0;
    }
    const bool cand = (lev < 3) && (rank < 9);

    __shared__ float siou[4][28];
    if (cand && vrow) siou[wid][lev * 9 + rank] = iou;   // candidate order == top_k
    __syncthreads();                                     // uniform: no early returns

    // mean + std(ddof=1) in the SAME k=0..26 sequence as the passing kernels
    float sum = 0.0f;
#pragma unroll
    for (int k = 0; k < NCAND; ++k) sum += siou[wid][k];
    const float mean = sum / (float)NCAND;
    float vs = 0.0f;
#pragma unroll
    for (int k = 0; k < NCAND; ++k) { float dd = siou[wid][k] - mean; vs += dd * dd; }
    const float thr = mean + sqrtf(vs / (float)(NCAND - 1));

    if (cand) {   // every (lev,rank<9) slot has exactly one owner -> full coverage
        unsigned int v = 0xFFFFFFFFu;
        if (vrow && iou > thr && mn > 1e-9f)             // strict >, EPS=1e-9
            v = (unsigned int)aidx | ((unsigned int)g << 14);   // aidx<2^14, g<2^6
        clist[row * NCAND + lev * 9 + rank] = v;
    }
}

// K23 (R8 structure + early vectorized scan): one block per (b, 84-anchor
// window) -> 1600 blocks. The batch's 1728-entry list is loaded as 432 uint4
// (2 register-staged iterations) ISSUED BEFORE the LDS zero + barrier, so the
// L2 latency hides under the zeroing. Scores streamed NT (46 MB > 8x4MiB L2,
// NT avoids L2 thrash -- R9 A/B proved plain stores regress).
__global__ __launch_bounds__(256) void k23_assign_scores(
        const float* __restrict__ anc, const int* __restrict__ glab,
        const float* __restrict__ gtb, const float* __restrict__ pdb,
        const unsigned int* __restrict__ clist, float* __restrict__ out) {
    const int tid = threadIdx.x;
    const int b = blockIdx.x / NWIN, win = blockIdx.x - b * NWIN;
    const int a0 = win * WND;

    __shared__ unsigned int lacc[WND];   // (count<<20) | sum_of_g
    __shared__ int   slbl[WND];
    __shared__ float sv[WND];

    // issue list loads first (432 uint4; thread gets e0 and maybe e1)
    const uint4* lst4 = (const uint4*)(clist + b * (NGT * NCAND));
    const int NE4 = (NGT * NCAND) / 4;               // 432
    uint4 e0 = make_uint4(0xFFFFFFFFu, 0xFFFFFFFFu, 0xFFFFFFFFu, 0xFFFFFFFFu);
    uint4 e1 = e0;
    e0 = lst4[tid];                                  // tid < 432 always (256<432)
    const bool has1 = (tid + 256) < NE4;             // threads 0..175
    if (has1) e1 = lst4[tid + 256];

    if (tid < WND) lacc[tid] = 0u;
    __syncthreads();

    // accumulate positives (order-independent packed add)
    {
        const unsigned int es[8] = {e0.x, e0.y, e0.z, e0.w, e1.x, e1.y, e1.z, e1.w};
#pragma unroll
        for (int j = 0; j < 8; ++j) {
            const unsigned int u = es[j];
            if (u != 0xFFFFFFFFu) {
                const int rel = (int)(u & 0x3FFFu) - a0;
                if (rel >= 0 && rel < WND)
                    atomicAdd(&lacc[rel], (1u << 20) | (u >> 14));
            }
        }
    }
    __syncthreads();

    if (tid < WND) {
        const int a = a0 + tid;
        const int idx = b * NA + a;
        const unsigned int acc = lacc[tid];
        const unsigned int fg = acc >> 20;
        int tgi = 0;
        if (fg == 1) {
            tgi = (int)(acc & 0xFFFFFu);             // sum of one g == that g
        } else if (fg > 1) {                         // argmax over ALL 64 gts
            const float4 ab = ((const float4*)anc)[a];
            float best = -1.0f; int gi = 0;
            for (int g = 0; g < NGT; ++g) {
                const float* gp = gtb + (b * NGT + g) * 4;
                float v = pair_iou(gp[0], gp[1], gp[2], gp[3], ab.x, ab.y, ab.z, ab.w);
                if (v > best) { best = v; gi = g; }
            }
            tgi = gi;
        }
        const bool pos = fg > 0;
        const int lbl = pos ? glab[b * NGT + tgi] : NCLS;
        const float4 gbox = ((const float4*)gtb)[b * NGT + tgi];

        float sval = 0.0f;
        if (pos) {
            // _batch_iou: clamped areas, union = a1+a2-ov+1e-9 (no max)
            const float4 pp = ((const float4*)pdb)[idx];
            float ltx = fmaxf(gbox.x, pp.x), lty = fmaxf(gbox.y, pp.y);
            float rbx = fminf(gbox.z, pp.z), rby = fminf(gbox.w, pp.w);
            float ov = fmaxf(rbx - ltx, 0.0f) * fmaxf(rby - lty, 0.0f);
            float a1 = fmaxf(gbox.z - gbox.x, 0.0f) * fmaxf(gbox.w - gbox.y, 0.0f);
            float a2 = fmaxf(pp.z - pp.x, 0.0f) * fmaxf(pp.w - pp.y, 0.0f);
            sval = ov / (a1 + a2 - ov + 1e-9f);
        }

        out[idx] = (float)lbl;                                 // target_labels
        ((float4*)(out + (size_t)BS * NA))[idx] = gbox;        // target_bboxes
        out[(size_t)BS * NA * 85 + idx] = pos ? 1.0f : 0.0f;   // fg_mask
        slbl[tid] = lbl; sv[tid] = sval;
    }
    __syncthreads();

    // stream scores NT: contiguous [ (b*NA+a0)*80, +WND*80 ) floats = 26.9 KB
    floatx4* ob = (floatx4*)(out + (size_t)BS * NA * 5 + ((size_t)b * NA + a0) * NCLS);
    for (int s = tid; s < WND * (NCLS / 4); s += 256) {
        const int lba = s / (NCLS / 4);
        const int q = s - lba * (NCLS / 4);
        const int lbl = slbl[lba];
        const float v = sv[lba];
        const int c0 = q * 4;
        floatx4 r;
        r.x = (c0     == lbl) ? v : 0.0f;
        r.y = (c0 + 1 == lbl) ? v : 0.0f;
        r.z = (c0 + 2 == lbl) ? v : 0.0f;
        r.w = (c0 + 3 == lbl) ? v : 0.0f;
        __builtin_nontemporal_store(r, &ob[s]);
    }
}

extern "C" void kernel_launch(void* const* d_in, const int* in_sizes, int n_in,
                              void* d_out, int out_size, void* d_ws, size_t ws_size,
                              hipStream_t stream) {
    const float* anc  = (const float*)d_in[0];
    const int*   glab = (const int*)d_in[1];
    const float* gtb  = (const float*)d_in[2];
    const float* mgt  = (const float*)d_in[3];
    const float* pdb  = (const float*)d_in[4];
    float* out = (float*)d_out;

    // ws: clist u32[BS*NGT*27] (~110 KB), fully rewritten every call
    unsigned int* clist = (unsigned int*)d_ws;

    k1_candidates<<<BS * NGT / 4, 256, 0, stream>>>(anc, gtb, mgt, clist);
    k23_assign_scores<<<BS * NWIN, 256, 0, stream>>>(anc, glab, gtb, pdb, clist, out);
}